// Round 1
// baseline (126.359 us; speedup 1.0000x reference)
//
#include <hip/hip_runtime.h>

typedef unsigned short u16;
typedef unsigned int   u32;

// ---- bf16 <-> f32 via bit ops (RNE pack) ----
__device__ __forceinline__ u16 f2b(float f) {
    u32 u = __float_as_uint(f);
    u32 r = (u + 0x7fffu + ((u >> 16) & 1u)) >> 16;
    return (u16)r;
}
__device__ __forceinline__ float b2f(u16 h) {
    return __uint_as_float(((u32)h) << 16);
}
__device__ __forceinline__ u32 pack2(float a, float b) {
    return (u32)f2b(a) | ((u32)f2b(b) << 16);
}
__device__ __forceinline__ void unpack8(uint4 r, float f[8]) {
    f[0] = b2f((u16)(r.x & 0xffffu)); f[1] = b2f((u16)(r.x >> 16));
    f[2] = b2f((u16)(r.y & 0xffffu)); f[3] = b2f((u16)(r.y >> 16));
    f[4] = b2f((u16)(r.z & 0xffffu)); f[5] = b2f((u16)(r.z >> 16));
    f[6] = b2f((u16)(r.w & 0xffffu)); f[7] = b2f((u16)(r.w >> 16));
}
// channel permutation: slot cc holds original channel perm(cc); involution.
__device__ __forceinline__ int permc(int c) { return ((c & 7) << 3) | (c >> 3); }

// ================= Kernel 1: q/k/v projections =================
// qt [n*64  + cc]        = q[n][perm(cc)]   (bf16)
// kvt[n*128 + cc]        = k[n][perm(cc)]   (bf16)
// kvt[n*128 + 64 + cc]   = v[n][perm(cc)]   (bf16)
__global__ __launch_bounds__(256) void qkv_kernel(
    const float* __restrict__ feat,
    const float* __restrict__ Wq, const float* __restrict__ bq,
    const float* __restrict__ Wk, const float* __restrict__ bk,
    const float* __restrict__ Wv, const float* __restrict__ bv,
    u16* __restrict__ qt, u16* __restrict__ kvt)
{
    __shared__ float fl[64][68];           // 64 rows of feat, padded (16B-aligned rows, no bank conflicts)
    __shared__ u16   wlb[3][64][64];       // weights bf16, columns permuted
    __shared__ float bl[3][64];            // biases, permuted
    const int t = threadIdx.x;

    for (int e = t; e < 4096; e += 256) {
        int i = e >> 6, c = e & 63;
        int pc = permc(c);
        wlb[0][i][pc] = f2b(Wq[e]);
        wlb[1][i][pc] = f2b(Wk[e]);
        wlb[2][i][pc] = f2b(Wv[e]);
    }
    if (t < 64) {
        int pc = permc(t);
        bl[0][pc] = bq[t]; bl[1][pc] = bk[t]; bl[2][pc] = bv[t];
    }
    const int rowbase = blockIdx.x * 64;
    for (int e4 = t; e4 < 1024; e4 += 256) {
        float4 v = *(const float4*)&feat[rowbase * 64 + e4 * 4];
        int elem = e4 * 4;
        *(float4*)&fl[elem >> 6][elem & 63] = v;
    }
    __syncthreads();

    const int r  = t >> 3;          // 0..31 ; handles rows r and r+32
    const int c0 = (t & 7) * 8;     // 8 consecutive (permuted) output cols
    float acc0[3][8], acc1[3][8];
#pragma unroll
    for (int m = 0; m < 3; m++)
#pragma unroll
        for (int x = 0; x < 8; x++) { acc0[m][x] = bl[m][c0 + x]; acc1[m][x] = acc0[m][x]; }

#pragma unroll 4
    for (int i = 0; i < 64; i++) {
        float f0 = fl[r][i], f1 = fl[r + 32][i];
#pragma unroll
        for (int m = 0; m < 3; m++) {
            uint4 wv = *(const uint4*)&wlb[m][i][c0];
            float w[8];
            unpack8(wv, w);
#pragma unroll
            for (int x = 0; x < 8; x++) {
                acc0[m][x] = fmaf(f0, w[x], acc0[m][x]);
                acc1[m][x] = fmaf(f1, w[x], acc1[m][x]);
            }
        }
    }

    // store both rows: q -> qt, k/v -> kvt (bf16, packed 16B stores)
#pragma unroll
    for (int rr = 0; rr < 2; rr++) {
        const float (*a)[8] = rr ? acc1 : acc0;
        int row = rowbase + r + rr * 32;
        uint4 pq, pk_, pv;
        pq.x  = pack2(a[0][0], a[0][1]); pq.y  = pack2(a[0][2], a[0][3]);
        pq.z  = pack2(a[0][4], a[0][5]); pq.w  = pack2(a[0][6], a[0][7]);
        pk_.x = pack2(a[1][0], a[1][1]); pk_.y = pack2(a[1][2], a[1][3]);
        pk_.z = pack2(a[1][4], a[1][5]); pk_.w = pack2(a[1][6], a[1][7]);
        pv.x  = pack2(a[2][0], a[2][1]); pv.y  = pack2(a[2][2], a[2][3]);
        pv.z  = pack2(a[2][4], a[2][5]); pv.w  = pack2(a[2][6], a[2][7]);
        *(uint4*)&qt [row * 64  + c0]      = pq;
        *(uint4*)&kvt[row * 128 + c0]      = pk_;
        *(uint4*)&kvt[row * 128 + 64 + c0] = pv;
    }
}

// ================= Kernel 2: fused gather + attention =================
// 8 lanes per point; lane l8 owns channels c = jv*8 + l8 (jv = 0..7 == s index),
// i.e. softmax column c2 = l8. Gathers read contiguous 16B thanks to permuted layout.
__global__ __launch_bounds__(256, 2) void attn_kernel(
    const float* __restrict__ point,
    const int*   __restrict__ idx,
    const u16*   __restrict__ qt,
    const u16*   __restrict__ kvt,
    const float* __restrict__ p_w1,   const float* __restrict__ p_b1,
    const float* __restrict__ p_bn_g, const float* __restrict__ p_bn_b,
    const float* __restrict__ p_bn_m, const float* __restrict__ p_bn_v,
    const float* __restrict__ p_w2,   const float* __restrict__ p_b2,
    const float* __restrict__ w_bn1_g, const float* __restrict__ w_bn1_b,
    const float* __restrict__ w_bn1_m, const float* __restrict__ w_bn1_v,
    const float* __restrict__ w_w1,    const float* __restrict__ w_b1,
    const float* __restrict__ w_bn2_g, const float* __restrict__ w_bn2_b,
    const float* __restrict__ w_bn2_m, const float* __restrict__ w_bn2_v,
    const float* __restrict__ w_w2,    const float* __restrict__ w_b2,
    float* __restrict__ out)
{
    const int t  = threadIdx.x;
    const int l8 = t & 7;
    const int n  = blockIdx.x * 32 + (t >> 3);
    const float EPS = 1e-5f;

    // ---- wave-uniform params (compiler scalarizes these loads) ----
    float pw1[9], pb1b[3], pbs[3], pbh[3];
#pragma unroll
    for (int i = 0; i < 9; i++) pw1[i] = p_w1[i];
#pragma unroll
    for (int a = 0; a < 3; a++) {
        float s = p_bn_g[a] * rsqrtf(p_bn_v[a] + EPS);
        pb1b[a] = p_b1[a];
        pbs[a] = s;
        pbh[a] = p_bn_b[a] - p_bn_m[a] * s;
    }
    float wb1[8], b2s[8], b2h[8];
#pragma unroll
    for (int h = 0; h < 8; h++) {
        wb1[h] = w_b1[h];
        float s = w_bn2_g[h] * rsqrtf(w_bn2_v[h] + EPS);
        b2s[h] = s;
        b2h[h] = w_bn2_b[h] - w_bn2_m[h] * s;
    }
    // ---- per-lane channel params, c = jv*8 + l8 ----
    float pw2r[3][8], pb2r[8], b1s[8], b1h[8], ww1r[8][8], ww2c[8];
#pragma unroll
    for (int jv = 0; jv < 8; jv++) {
        int c = jv * 8 + l8;
        pw2r[0][jv] = p_w2[c];
        pw2r[1][jv] = p_w2[64 + c];
        pw2r[2][jv] = p_w2[128 + c];
        pb2r[jv] = p_b2[c];
        float s = w_bn1_g[c] * rsqrtf(w_bn1_v[c] + EPS);
        b1s[jv] = s;
        b1h[jv] = w_bn1_b[c] - w_bn1_m[c] * s;
#pragma unroll
        for (int h = 0; h < 8; h++) ww1r[jv][h] = w_w1[c * 8 + h];
    }
#pragma unroll
    for (int h = 0; h < 8; h++) ww2c[h] = w_w2[h * 8 + l8];
    const float wb2l = w_b2[l8];

    // ---- per-point state ----
    float q[8];
    {
        uint4 qr = *(const uint4*)&qt[n * 64 + l8 * 8];
        unpack8(qr, q);
    }
    const float px = point[n * 3 + 0], py = point[n * 3 + 1], pz = point[n * 3 + 2];
    float acc[8];
#pragma unroll
    for (int jv = 0; jv < 8; jv++) acc[jv] = 0.f;

    // software-pipelined neighbor loop (1-iter lookahead on gathers)
    int j = idx[n * 16];
    uint4 kr = *(const uint4*)&kvt[j * 128 + l8 * 8];
    uint4 vr = *(const uint4*)&kvt[j * 128 + 64 + l8 * 8];
    float jx = point[j * 3], jy = point[j * 3 + 1], jz = point[j * 3 + 2];

#pragma unroll 2
    for (int kk = 0; kk < 16; kk++) {
        int kk1 = kk < 15 ? kk + 1 : 15;
        int jn = idx[n * 16 + kk1];
        uint4 krn = *(const uint4*)&kvt[jn * 128 + l8 * 8];
        uint4 vrn = *(const uint4*)&kvt[jn * 128 + 64 + l8 * 8];
        float jxn = point[jn * 3], jyn = point[jn * 3 + 1], jzn = point[jn * 3 + 2];

        // linear_p first stage: 3->3 dense + BN + ReLU (per-neighbor scalars)
        float dx = jx - px, dy = jy - py, dz = jz - pz;
        float t0 = fmaxf(0.f, (dx * pw1[0] + dy * pw1[3] + dz * pw1[6] + pb1b[0]) * pbs[0] + pbh[0]);
        float t1 = fmaxf(0.f, (dx * pw1[1] + dy * pw1[4] + dz * pw1[7] + pb1b[1]) * pbs[1] + pbh[1]);
        float t2 = fmaxf(0.f, (dx * pw1[2] + dy * pw1[5] + dz * pw1[8] + pb1b[2]) * pbs[2] + pbh[2]);

        float kf[8], vf[8];
        unpack8(kr, kf);
        unpack8(vr, vf);

        float partial[8];
#pragma unroll
        for (int h = 0; h < 8; h++) partial[h] = 0.f;
        float vp[8];
#pragma unroll
        for (int jv = 0; jv < 8; jv++) {
            // p = linear_p second stage (3 -> 64), channel c = jv*8+l8
            float pj = t0 * pw2r[0][jv] + t1 * pw2r[1][jv] + t2 * pw2r[2][jv] + pb2r[jv];
            // w = relu(bn1(k - q + p))
            float w64 = fmaxf(0.f, (kf[jv] - q[jv] + pj) * b1s[jv] + b1h[jv]);
            vp[jv] = vf[jv] + pj;
#pragma unroll
            for (int h = 0; h < 8; h++) partial[h] = fmaf(w64, ww1r[jv][h], partial[h]);
        }
        // reduce 64->8 across the 8-lane group (butterfly)
#pragma unroll
        for (int mask = 1; mask < 8; mask <<= 1)
#pragma unroll
            for (int h = 0; h < 8; h++) partial[h] += __shfl_xor(partial[h], mask, 8);

        // relu(bn2(.)) @ w_w2 -> this lane's softmax logit (c2 = l8)
        float y = wb2l;
#pragma unroll
        for (int h = 0; h < 8; h++) {
            float wb = fmaxf(0.f, (partial[h] + wb1[h]) * b2s[h] + b2h[h]);
            y = fmaf(wb, ww2c[h], y);
        }
        // softmax over c2 (the 8 lanes of the group)
        float mx = y;
#pragma unroll
        for (int mask = 1; mask < 8; mask <<= 1) mx = fmaxf(mx, __shfl_xor(mx, mask, 8));
        float e = __expf(y - mx);
        float ssum = e;
#pragma unroll
        for (int mask = 1; mask < 8; mask <<= 1) ssum += __shfl_xor(ssum, mask, 8);
        float sm = e / ssum;

#pragma unroll
        for (int jv = 0; jv < 8; jv++) acc[jv] = fmaf(vp[jv], sm, acc[jv]);

        kr = krn; vr = vrn; jx = jxn; jy = jyn; jz = jzn; j = jn;
    }

#pragma unroll
    for (int jv = 0; jv < 8; jv++) out[n * 64 + jv * 8 + l8] = acc[jv];
}

extern "C" void kernel_launch(void* const* d_in, const int* in_sizes, int n_in,
                              void* d_out, int out_size, void* d_ws, size_t ws_size,
                              hipStream_t stream)
{
    const float* point   = (const float*)d_in[0];
    const float* feat    = (const float*)d_in[1];
    const int*   idx     = (const int*)d_in[2];
    const float* Wq      = (const float*)d_in[3];
    const float* bq      = (const float*)d_in[4];
    const float* Wk      = (const float*)d_in[5];
    const float* bk      = (const float*)d_in[6];
    const float* Wv      = (const float*)d_in[7];
    const float* bv      = (const float*)d_in[8];
    const float* p_w1    = (const float*)d_in[9];
    const float* p_b1    = (const float*)d_in[10];
    const float* p_bn_g  = (const float*)d_in[11];
    const float* p_bn_b  = (const float*)d_in[12];
    const float* p_bn_m  = (const float*)d_in[13];
    const float* p_bn_v  = (const float*)d_in[14];
    const float* p_w2    = (const float*)d_in[15];
    const float* p_b2    = (const float*)d_in[16];
    const float* w_bn1_g = (const float*)d_in[17];
    const float* w_bn1_b = (const float*)d_in[18];
    const float* w_bn1_m = (const float*)d_in[19];
    const float* w_bn1_v = (const float*)d_in[20];
    const float* w_w1    = (const float*)d_in[21];
    const float* w_b1    = (const float*)d_in[22];
    const float* w_bn2_g = (const float*)d_in[23];
    const float* w_bn2_b = (const float*)d_in[24];
    const float* w_bn2_m = (const float*)d_in[25];
    const float* w_bn2_v = (const float*)d_in[26];
    const float* w_w2    = (const float*)d_in[27];
    const float* w_b2    = (const float*)d_in[28];
    float* out = (float*)d_out;

    const int N = in_sizes[0] / 3;   // 65536

    // workspace: kvt = N*128 bf16 (16.8MB), qt = N*64 bf16 (8.4MB) => 25.2MB
    u16* kvt = (u16*)d_ws;
    u16* qt  = (u16*)d_ws + (size_t)N * 128;

    qkv_kernel<<<N / 64, 256, 0, stream>>>(feat, Wq, bq, Wk, bk, Wv, bv, qt, kvt);
    attn_kernel<<<N / 32, 256, 0, stream>>>(point, idx, qt, kvt,
                                            p_w1, p_b1, p_bn_g, p_bn_b, p_bn_m, p_bn_v, p_w2, p_b2,
                                            w_bn1_g, w_bn1_b, w_bn1_m, w_bn1_v, w_w1, w_b1,
                                            w_bn2_g, w_bn2_b, w_bn2_m, w_bn2_v, w_w2, w_b2,
                                            out);
}